// Round 4
// baseline (1088.852 us; speedup 1.0000x reference)
//
#include <hip/hip_runtime.h>

#define N_NODES 100000
#define NEDGE   3200000
#define F_IN    512
#define HID     16
#define NCLS    40

#define NBKT    782           /* buckets of 128 dst nodes: ceil(100000/128) */
#define BCAP    4480          /* mean 4096 + 6 sigma; fixed input -> safe   */
#define SC_EPB  5120          /* edges per scatter block: 256 thr x 20      */
#define SC_NB   (NEDGE / SC_EPB)   /* 625 exact */

typedef __bf16 bf16x8 __attribute__((ext_vector_type(8)));
typedef float floatx4 __attribute__((ext_vector_type(4)));

// ============ bucketing scatter: edges -> per-dst-bucket packed words ============
// word = src | (local_dst << 17);  src < 2^17, local_dst < 128.
// All random placement happens in LDS; global writes are coalesced segment flushes.
__global__ __launch_bounds__(256) void k_scatter(const int* __restrict__ src,
                                                 const int* __restrict__ dst,
                                                 int* __restrict__ bcnt,
                                                 int* __restrict__ packed) {
    __shared__ int hist[784];
    __shared__ int hstart[784];
    __shared__ int cursor[784];
    __shared__ int gbase[784];
    __shared__ int stage[SC_EPB];
    __shared__ int red[256];
    int t = threadIdx.x;
    for (int i = t; i < 784; i += 256) hist[i] = 0;
    __syncthreads();

    int base = blockIdx.x * SC_EPB;
    int dreg[20], sreg[20];
    #pragma unroll
    for (int r = 0; r < 5; r++) {
        int4 d4 = *(const int4*)(dst + base + r * 1024 + t * 4);
        int4 s4 = *(const int4*)(src + base + r * 1024 + t * 4);
        dreg[r*4+0] = d4.x; dreg[r*4+1] = d4.y; dreg[r*4+2] = d4.z; dreg[r*4+3] = d4.w;
        sreg[r*4+0] = s4.x; sreg[r*4+1] = s4.y; sreg[r*4+2] = s4.z; sreg[r*4+3] = s4.w;
    }
    #pragma unroll
    for (int j = 0; j < 20; j++) atomicAdd(&hist[dreg[j] >> 7], 1);
    __syncthreads();

    // block-local exclusive scan of hist[0..783]: thread owns 4 buckets
    int a0 = 0, a1 = 0, a2 = 0, a3 = 0, ls = 0;
    if (t < 196) {
        a0 = hist[4*t]; a1 = hist[4*t+1]; a2 = hist[4*t+2]; a3 = hist[4*t+3];
        ls = a0 + a1 + a2 + a3;
    }
    red[t] = ls; __syncthreads();
    for (int off = 1; off < 256; off <<= 1) {
        int add = (t >= off) ? red[t - off] : 0;
        __syncthreads();
        red[t] += add;
        __syncthreads();
    }
    if (t < 196) {
        int ex = red[t] - ls;
        hstart[4*t]   = ex;
        hstart[4*t+1] = ex + a0;
        hstart[4*t+2] = ex + a0 + a1;
        hstart[4*t+3] = ex + a0 + a1 + a2;
    }
    __syncthreads();
    for (int i = t; i < 784; i += 256) cursor[i] = hstart[i];
    __syncthreads();

    #pragma unroll
    for (int j = 0; j < 20; j++) {
        int b = dreg[j] >> 7;
        int pos = atomicAdd(&cursor[b], 1);
        stage[pos] = sreg[j] | ((dreg[j] & 127) << 17);
    }
    __syncthreads();

    for (int b = t; b < 784; b += 256) {
        int c = hist[b];
        gbase[b] = c ? atomicAdd(&bcnt[b], c) : 0;   // hist[>=782]==0, no OOB atomic
    }
    __syncthreads();

    int w = t >> 6, lane = t & 63;
    for (int b = w; b < NBKT; b += 4) {
        int c = hist[b];
        if (!c) continue;
        int gb = gbase[b], st = hstart[b];
        int lim = min(c, BCAP - gb);                  // safety clamp (never expected)
        long long o = (long long)b * BCAP + gb;
        for (int i = lane; i < lim; i += 64) packed[o + i] = stage[st + i];
    }
}

// ============ deg + dinv from bucketed words (LDS histogram, no global atomics) ============
__global__ void k_dinvB(const int* __restrict__ bcnt, const int* __restrict__ packed,
                        float* __restrict__ dinv) {
    __shared__ int h[128];
    int b = blockIdx.x, t = threadIdx.x;
    if (t < 128) h[t] = 0;
    __syncthreads();
    int c = min(bcnt[b], BCAP);
    const int* wp = packed + (long long)b * BCAP;
    for (int i = t; i < c; i += 256) atomicAdd(&h[wp[i] >> 17], 1);
    __syncthreads();
    if (t < 128) {
        int v = b * 128 + t;
        if (v < N_NODES) dinv[v] = rsqrtf((float)(h[t] + 1));
    }
}

// ============ GEMM1: h1s = dinv * (x @ W1), bf16 MFMA hi/lo split ============
__global__ __launch_bounds__(256) void k_gemm1(const float* __restrict__ x,
                                               const float* __restrict__ W1,
                                               const float* __restrict__ dinv,
                                               float* __restrict__ h1s) {
    __shared__ __bf16 wh[16 * 64 * 8];
    __shared__ __bf16 wl[16 * 64 * 8];
    int t = threadIdx.x;
    for (int e = t; e < 8192; e += 256) {
        int c = e >> 9, l = (e >> 3) & 63, j = e & 7;
        int k = c * 32 + ((l >> 4) << 3) + j;
        int n = l & 15;
        float wv = W1[k * HID + n];
        __bf16 h = (__bf16)wv;
        wh[e] = h;
        wl[e] = (__bf16)(wv - (float)h);
    }
    __syncthreads();

    int wave = t >> 6, lane = t & 63;
    int q = lane >> 4, m = lane & 15;
    int row0 = blockIdx.x * 64 + wave * 16;
    int rowa = row0 + m;
    if (rowa >= N_NODES) rowa = N_NODES - 1;
    const float* xr = x + (size_t)rowa * F_IN + q * 8;

    floatx4 acc = {0.f, 0.f, 0.f, 0.f};
    #pragma unroll 4
    for (int c = 0; c < 16; c++) {
        float4 a0 = *(const float4*)(xr + c * 32);
        float4 a1 = *(const float4*)(xr + c * 32 + 4);
        float xv[8] = {a0.x, a0.y, a0.z, a0.w, a1.x, a1.y, a1.z, a1.w};
        bf16x8 ah, al;
        #pragma unroll
        for (int j = 0; j < 8; j++) {
            __bf16 h = (__bf16)xv[j];
            ah[j] = h;
            al[j] = (__bf16)(xv[j] - (float)h);
        }
        bf16x8 bh = *(const bf16x8*)&wh[(c * 64 + lane) * 8];
        bf16x8 bl = *(const bf16x8*)&wl[(c * 64 + lane) * 8];
        acc = __builtin_amdgcn_mfma_f32_16x16x32_bf16(ah, bh, acc, 0, 0, 0);
        acc = __builtin_amdgcn_mfma_f32_16x16x32_bf16(ah, bl, acc, 0, 0, 0);
        acc = __builtin_amdgcn_mfma_f32_16x16x32_bf16(al, bh, acc, 0, 0, 0);
    }
    #pragma unroll
    for (int r = 0; r < 4; r++) {
        int grow = row0 + q * 4 + r;
        if (grow < N_NODES) h1s[grow * HID + (lane & 15)] = dinv[grow] * acc[r];
    }
}

// ============ layer-1 aggregate in LDS + bias + relu; output pre-scaled by dinv ============
__global__ __launch_bounds__(256) void k_agg1B(const float* __restrict__ h1s,
                                               const int* __restrict__ packed,
                                               const int* __restrict__ bcnt,
                                               const float* __restrict__ dinv,
                                               const float* __restrict__ b1,
                                               float* __restrict__ ys) {
    __shared__ float acc[128 * 17];   // stride 17: scrambles LDS banks
    int b = blockIdx.x, t = threadIdx.x;
    for (int i = t; i < 128 * 17; i += 256) acc[i] = 0.f;
    __syncthreads();
    int c = min(bcnt[b], BCAP);
    const int* wp = packed + (long long)b * BCAP;
    int slot = t >> 4, k = t & 15;    // 16 lanes per edge, lane k = feature k
    for (int i = slot; i < c; i += 16) {
        int w = wp[i];
        int s = w & 0x1FFFF, ld = w >> 17;
        atomicAdd(&acc[ld * 17 + k], h1s[s * 16 + k]);
    }
    __syncthreads();
    for (int i = t; i < 128 * 16; i += 256) {
        int vl = i >> 4, kk = i & 15;
        int v = b * 128 + vl;
        if (v < N_NODES) {
            float dv = dinv[v];
            float sum = acc[vl * 17 + kk] + h1s[v * 16 + kk];   // + self loop
            float val = fmaxf(dv * sum + b1[kk], 0.f);
            ys[v * 16 + kk] = dv * val;                         // pre-scale for layer 2
        }
    }
}

// ============ layer-2 aggregate in LDS + W2 (16->40) + bias + log_softmax ============
__global__ __launch_bounds__(256) void k_agg2B(const float* __restrict__ ys,
                                               const int* __restrict__ packed,
                                               const int* __restrict__ bcnt,
                                               const float* __restrict__ dinv,
                                               const float* __restrict__ W2,
                                               const float* __restrict__ b2,
                                               float* __restrict__ out) {
    __shared__ float acc[128 * 17];
    __shared__ float w2s[HID * NCLS];
    __shared__ float b2s[NCLS];
    int b = blockIdx.x, t = threadIdx.x;
    for (int i = t; i < 128 * 17; i += 256) acc[i] = 0.f;
    for (int i = t; i < HID * NCLS; i += 256) w2s[i] = W2[i];
    if (t < NCLS) b2s[t] = b2[t];
    __syncthreads();
    int c = min(bcnt[b], BCAP);
    const int* wp = packed + (long long)b * BCAP;
    int slot = t >> 4, k = t & 15;
    for (int i = slot; i < c; i += 16) {
        int w = wp[i];
        int s = w & 0x1FFFF, ld = w >> 17;
        atomicAdd(&acc[ld * 17 + k], ys[s * 16 + k]);
    }
    __syncthreads();
    if (t < 128) {
        int v = b * 128 + t;
        if (v < N_NODES) {
            float dv = dinv[v];
            float tv[16];
            #pragma unroll
            for (int kk = 0; kk < 16; kk++) tv[kk] = dv * (acc[t * 17 + kk] + ys[v * 16 + kk]);
            float lg[NCLS];
            float mx = -1e30f;
            #pragma unroll
            for (int cc = 0; cc < NCLS; cc++) {
                float a = b2s[cc];
                #pragma unroll
                for (int kk = 0; kk < 16; kk++) a = fmaf(tv[kk], w2s[kk * NCLS + cc], a);
                lg[cc] = a;
                mx = fmaxf(mx, a);
            }
            float ssum = 0.f;
            #pragma unroll
            for (int cc = 0; cc < NCLS; cc++) ssum += __expf(lg[cc] - mx);
            float lse = mx + __logf(ssum);
            float* op = out + (long long)v * NCLS;
            #pragma unroll
            for (int cc = 0; cc < NCLS; cc++) op[cc] = lg[cc] - lse;
        }
    }
}

extern "C" void kernel_launch(void* const* d_in, const int* in_sizes, int n_in,
                              void* d_out, int out_size, void* d_ws, size_t ws_size,
                              hipStream_t stream) {
    const float* x  = (const float*)d_in[0];
    const int*   ei = (const int*)d_in[1];
    const float* W1 = (const float*)d_in[2];
    const float* b1 = (const float*)d_in[3];
    const float* W2 = (const float*)d_in[4];
    const float* b2 = (const float*)d_in[5];
    float* out = (float*)d_out;
    const int* src = ei;
    const int* dst = ei + NEDGE;

    char* w = (char*)d_ws;
    size_t o = 0;
    auto alloc = [&](size_t bytes) -> char* {
        char* p = w + o;
        o += (bytes + 511) & ~(size_t)511;
        return p;
    };
    int*   bcnt   = (int*)alloc((size_t)NBKT * 4);
    float* dinv   = (float*)alloc((size_t)N_NODES * 4);
    int*   packed = (int*)alloc((size_t)NBKT * BCAP * 4);   // 14.0 MB
    float* h1s    = (float*)alloc((size_t)N_NODES * HID * 4);
    float* ys     = (float*)alloc((size_t)N_NODES * HID * 4);

    hipMemsetAsync(bcnt, 0, (size_t)NBKT * 4, stream);

    k_scatter<<<SC_NB, 256, 0, stream>>>(src, dst, bcnt, packed);
    k_dinvB<<<NBKT, 256, 0, stream>>>(bcnt, packed, dinv);
    k_gemm1<<<(N_NODES + 63) / 64, 256, 0, stream>>>(x, W1, dinv, h1s);
    k_agg1B<<<NBKT, 256, 0, stream>>>(h1s, packed, bcnt, dinv, b1, ys);
    k_agg2B<<<NBKT, 256, 0, stream>>>(ys, packed, bcnt, dinv, W2, b2, out);
}

// Round 5
// 1028.188 us; speedup vs baseline: 1.0590x; 1.0590x over previous
//
#include <hip/hip_runtime.h>

#define N_NODES 100000
#define NEDGE   3200000
#define F_IN    512
#define HID     16
#define NCLS    40

#define NBKT    782           /* buckets of 128 dst nodes: ceil(100000/128) */
#define BCAP    4480          /* mean 4096 + 6 sigma; fixed input -> safe   */
#define SC_EPB  5120          /* edges per scatter block: 256 thr x 20      */
#define SC_NB   (NEDGE / SC_EPB)   /* 625 exact */

typedef __bf16 bf16x8 __attribute__((ext_vector_type(8)));
typedef float floatx4 __attribute__((ext_vector_type(4)));

// ============ bucketing scatter: edges -> per-dst-bucket packed words ============
// word = src | (local_dst << 17);  src < 2^17, local_dst < 128.
// Random placement in LDS; bucket id remembered per slot -> flush is one
// fully-parallel coalesced pass.
__global__ __launch_bounds__(256) void k_scatter(const int* __restrict__ src,
                                                 const int* __restrict__ dst,
                                                 int* __restrict__ bcnt,
                                                 int* __restrict__ packed) {
    __shared__ int hist[784];
    __shared__ int hstart[784];
    __shared__ int cursor[784];
    __shared__ int gbase[784];
    __shared__ int stage[SC_EPB];
    __shared__ unsigned short sbk[SC_EPB];
    __shared__ int red[256];
    int t = threadIdx.x;
    for (int i = t; i < 784; i += 256) hist[i] = 0;
    __syncthreads();

    int base = blockIdx.x * SC_EPB;
    int dreg[20], sreg[20];
    #pragma unroll
    for (int r = 0; r < 5; r++) {
        int4 d4 = *(const int4*)(dst + base + r * 1024 + t * 4);
        int4 s4 = *(const int4*)(src + base + r * 1024 + t * 4);
        dreg[r*4+0] = d4.x; dreg[r*4+1] = d4.y; dreg[r*4+2] = d4.z; dreg[r*4+3] = d4.w;
        sreg[r*4+0] = s4.x; sreg[r*4+1] = s4.y; sreg[r*4+2] = s4.z; sreg[r*4+3] = s4.w;
    }
    #pragma unroll
    for (int j = 0; j < 20; j++) atomicAdd(&hist[dreg[j] >> 7], 1);
    __syncthreads();

    // block-local exclusive scan of hist[0..783]: thread owns 4 buckets
    int a0 = 0, a1 = 0, a2 = 0, a3 = 0, ls = 0;
    if (t < 196) {
        a0 = hist[4*t]; a1 = hist[4*t+1]; a2 = hist[4*t+2]; a3 = hist[4*t+3];
        ls = a0 + a1 + a2 + a3;
    }
    red[t] = ls; __syncthreads();
    for (int off = 1; off < 256; off <<= 1) {
        int add = (t >= off) ? red[t - off] : 0;
        __syncthreads();
        red[t] += add;
        __syncthreads();
    }
    if (t < 196) {
        int ex = red[t] - ls;
        hstart[4*t]   = ex;
        hstart[4*t+1] = ex + a0;
        hstart[4*t+2] = ex + a0 + a1;
        hstart[4*t+3] = ex + a0 + a1 + a2;
    }
    __syncthreads();
    for (int i = t; i < 784; i += 256) cursor[i] = hstart[i];
    __syncthreads();

    #pragma unroll
    for (int j = 0; j < 20; j++) {
        int b = dreg[j] >> 7;
        int pos = atomicAdd(&cursor[b], 1);
        stage[pos] = sreg[j] | ((dreg[j] & 127) << 17);
        sbk[pos] = (unsigned short)b;
    }
    __syncthreads();

    for (int b = t; b < 784; b += 256) {
        int c = hist[b];
        gbase[b] = c ? atomicAdd(&bcnt[b], c) : 0;   // hist[>=782]==0, no OOB atomic
    }
    __syncthreads();

    // parallel coalesced flush: every thread handles 20 staged words
    for (int i = t; i < SC_EPB; i += 256) {
        int b = sbk[i];
        int off = gbase[b] + (i - hstart[b]);
        if (off < BCAP) packed[(long long)b * BCAP + off] = stage[i];
    }
}

// ============ deg + dinv from bucketed words (LDS histogram) ============
__global__ void k_dinvB(const int* __restrict__ bcnt, const int* __restrict__ packed,
                        float* __restrict__ dinv) {
    __shared__ int h[128];
    int b = blockIdx.x, t = threadIdx.x;
    if (t < 128) h[t] = 0;
    __syncthreads();
    int c = min(bcnt[b], BCAP);
    const int* wp = packed + (long long)b * BCAP;
    for (int i = t; i < c; i += 256) atomicAdd(&h[wp[i] >> 17], 1);
    __syncthreads();
    if (t < 128) {
        int v = b * 128 + t;
        if (v < N_NODES) dinv[v] = rsqrtf((float)(h[t] + 1));
    }
}

// ============ GEMM1: h1s = dinv * (x @ W1), bf16 MFMA hi/lo split ============
__global__ __launch_bounds__(256) void k_gemm1(const float* __restrict__ x,
                                               const float* __restrict__ W1,
                                               const float* __restrict__ dinv,
                                               float* __restrict__ h1s) {
    __shared__ __bf16 wh[16 * 64 * 8];
    __shared__ __bf16 wl[16 * 64 * 8];
    int t = threadIdx.x;
    for (int e = t; e < 8192; e += 256) {
        int c = e >> 9, l = (e >> 3) & 63, j = e & 7;
        int k = c * 32 + ((l >> 4) << 3) + j;
        int n = l & 15;
        float wv = W1[k * HID + n];
        __bf16 h = (__bf16)wv;
        wh[e] = h;
        wl[e] = (__bf16)(wv - (float)h);
    }
    __syncthreads();

    int wave = t >> 6, lane = t & 63;
    int q = lane >> 4, m = lane & 15;
    int row0 = blockIdx.x * 64 + wave * 16;
    int rowa = row0 + m;
    if (rowa >= N_NODES) rowa = N_NODES - 1;
    const float* xr = x + (size_t)rowa * F_IN + q * 8;

    floatx4 acc = {0.f, 0.f, 0.f, 0.f};
    #pragma unroll 4
    for (int c = 0; c < 16; c++) {
        float4 a0 = *(const float4*)(xr + c * 32);
        float4 a1 = *(const float4*)(xr + c * 32 + 4);
        float xv[8] = {a0.x, a0.y, a0.z, a0.w, a1.x, a1.y, a1.z, a1.w};
        bf16x8 ah, al;
        #pragma unroll
        for (int j = 0; j < 8; j++) {
            __bf16 h = (__bf16)xv[j];
            ah[j] = h;
            al[j] = (__bf16)(xv[j] - (float)h);
        }
        bf16x8 bh = *(const bf16x8*)&wh[(c * 64 + lane) * 8];
        bf16x8 bl = *(const bf16x8*)&wl[(c * 64 + lane) * 8];
        acc = __builtin_amdgcn_mfma_f32_16x16x32_bf16(ah, bh, acc, 0, 0, 0);
        acc = __builtin_amdgcn_mfma_f32_16x16x32_bf16(ah, bl, acc, 0, 0, 0);
        acc = __builtin_amdgcn_mfma_f32_16x16x32_bf16(al, bh, acc, 0, 0, 0);
    }
    #pragma unroll
    for (int r = 0; r < 4; r++) {
        int grow = row0 + q * 4 + r;
        if (grow < N_NODES) h1s[grow * HID + (lane & 15)] = dinv[grow] * acc[r];
    }
}

// ============ layer-1 aggregate in LDS; 4 lanes/edge float4, UF=4 MLP ============
__global__ __launch_bounds__(512) void k_agg1B(const float* __restrict__ h1s,
                                               const int* __restrict__ packed,
                                               const int* __restrict__ bcnt,
                                               const float* __restrict__ dinv,
                                               const float* __restrict__ b1,
                                               float* __restrict__ ys) {
    __shared__ float acc[128 * 17];   // stride 17: scrambles LDS banks
    int b = blockIdx.x, t = threadIdx.x;
    for (int i = t; i < 128 * 17; i += 512) acc[i] = 0.f;
    __syncthreads();
    int c = min(bcnt[b], BCAP);
    const int* wp = packed + (long long)b * BCAP;
    int g = t >> 2, k4 = (t & 3) << 2;   // 4 lanes per edge, lane covers 4 feats
    int i = g;
    for (; i + 384 < c; i += 512) {
        int w0 = wp[i], w1 = wp[i + 128], w2 = wp[i + 256], w3 = wp[i + 384];
        float4 g0 = *(const float4*)(h1s + (w0 & 0x1FFFF) * 16 + k4);
        float4 g1 = *(const float4*)(h1s + (w1 & 0x1FFFF) * 16 + k4);
        float4 g2 = *(const float4*)(h1s + (w2 & 0x1FFFF) * 16 + k4);
        float4 g3 = *(const float4*)(h1s + (w3 & 0x1FFFF) * 16 + k4);
        float* p0 = &acc[(w0 >> 17) * 17 + k4];
        float* p1 = &acc[(w1 >> 17) * 17 + k4];
        float* p2 = &acc[(w2 >> 17) * 17 + k4];
        float* p3 = &acc[(w3 >> 17) * 17 + k4];
        atomicAdd(p0 + 0, g0.x); atomicAdd(p0 + 1, g0.y); atomicAdd(p0 + 2, g0.z); atomicAdd(p0 + 3, g0.w);
        atomicAdd(p1 + 0, g1.x); atomicAdd(p1 + 1, g1.y); atomicAdd(p1 + 2, g1.z); atomicAdd(p1 + 3, g1.w);
        atomicAdd(p2 + 0, g2.x); atomicAdd(p2 + 1, g2.y); atomicAdd(p2 + 2, g2.z); atomicAdd(p2 + 3, g2.w);
        atomicAdd(p3 + 0, g3.x); atomicAdd(p3 + 1, g3.y); atomicAdd(p3 + 2, g3.z); atomicAdd(p3 + 3, g3.w);
    }
    for (; i < c; i += 128) {
        int w = wp[i];
        float4 gg = *(const float4*)(h1s + (w & 0x1FFFF) * 16 + k4);
        float* p = &acc[(w >> 17) * 17 + k4];
        atomicAdd(p + 0, gg.x); atomicAdd(p + 1, gg.y); atomicAdd(p + 2, gg.z); atomicAdd(p + 3, gg.w);
    }
    __syncthreads();
    for (int ii = t; ii < 128 * 16; ii += 512) {
        int vl = ii >> 4, kk = ii & 15;
        int v = b * 128 + vl;
        if (v < N_NODES) {
            float dv = dinv[v];
            float sum = acc[vl * 17 + kk] + h1s[v * 16 + kk];   // + self loop
            float val = fmaxf(dv * sum + b1[kk], 0.f);
            ys[v * 16 + kk] = dv * val;                         // pre-scale for layer 2
        }
    }
}

// ============ layer-2 aggregate in LDS + W2 (16->40) + bias + log_softmax ============
__global__ __launch_bounds__(512) void k_agg2B(const float* __restrict__ ys,
                                               const int* __restrict__ packed,
                                               const int* __restrict__ bcnt,
                                               const float* __restrict__ dinv,
                                               const float* __restrict__ W2,
                                               const float* __restrict__ b2,
                                               float* __restrict__ out) {
    __shared__ float acc[128 * 17];
    __shared__ float w2s[HID * NCLS];
    __shared__ float b2s[NCLS];
    int b = blockIdx.x, t = threadIdx.x;
    for (int i = t; i < 128 * 17; i += 512) acc[i] = 0.f;
    for (int i = t; i < HID * NCLS; i += 512) w2s[i] = W2[i];
    if (t < NCLS) b2s[t] = b2[t];
    __syncthreads();
    int c = min(bcnt[b], BCAP);
    const int* wp = packed + (long long)b * BCAP;
    int g = t >> 2, k4 = (t & 3) << 2;
    int i = g;
    for (; i + 384 < c; i += 512) {
        int w0 = wp[i], w1 = wp[i + 128], w2 = wp[i + 256], w3 = wp[i + 384];
        float4 g0 = *(const float4*)(ys + (w0 & 0x1FFFF) * 16 + k4);
        float4 g1 = *(const float4*)(ys + (w1 & 0x1FFFF) * 16 + k4);
        float4 g2 = *(const float4*)(ys + (w2 & 0x1FFFF) * 16 + k4);
        float4 g3 = *(const float4*)(ys + (w3 & 0x1FFFF) * 16 + k4);
        float* p0 = &acc[(w0 >> 17) * 17 + k4];
        float* p1 = &acc[(w1 >> 17) * 17 + k4];
        float* p2 = &acc[(w2 >> 17) * 17 + k4];
        float* p3 = &acc[(w3 >> 17) * 17 + k4];
        atomicAdd(p0 + 0, g0.x); atomicAdd(p0 + 1, g0.y); atomicAdd(p0 + 2, g0.z); atomicAdd(p0 + 3, g0.w);
        atomicAdd(p1 + 0, g1.x); atomicAdd(p1 + 1, g1.y); atomicAdd(p1 + 2, g1.z); atomicAdd(p1 + 3, g1.w);
        atomicAdd(p2 + 0, g2.x); atomicAdd(p2 + 1, g2.y); atomicAdd(p2 + 2, g2.z); atomicAdd(p2 + 3, g2.w);
        atomicAdd(p3 + 0, g3.x); atomicAdd(p3 + 1, g3.y); atomicAdd(p3 + 2, g3.z); atomicAdd(p3 + 3, g3.w);
    }
    for (; i < c; i += 128) {
        int w = wp[i];
        float4 gg = *(const float4*)(ys + (w & 0x1FFFF) * 16 + k4);
        float* p = &acc[(w >> 17) * 17 + k4];
        atomicAdd(p + 0, gg.x); atomicAdd(p + 1, gg.y); atomicAdd(p + 2, gg.z); atomicAdd(p + 3, gg.w);
    }
    __syncthreads();
    if (t < 128) {
        int v = b * 128 + t;
        if (v < N_NODES) {
            float dv = dinv[v];
            float tv[16];
            #pragma unroll
            for (int kk = 0; kk < 16; kk++) tv[kk] = dv * (acc[t * 17 + kk] + ys[v * 16 + kk]);
            float lg[NCLS];
            float mx = -1e30f;
            #pragma unroll
            for (int cc = 0; cc < NCLS; cc++) {
                float a = b2s[cc];
                #pragma unroll
                for (int kk = 0; kk < 16; kk++) a = fmaf(tv[kk], w2s[kk * NCLS + cc], a);
                lg[cc] = a;
                mx = fmaxf(mx, a);
            }
            float ssum = 0.f;
            #pragma unroll
            for (int cc = 0; cc < NCLS; cc++) ssum += __expf(lg[cc] - mx);
            float lse = mx + __logf(ssum);
            float* op = out + (long long)v * NCLS;
            #pragma unroll
            for (int cc = 0; cc < NCLS; cc++) op[cc] = lg[cc] - lse;
        }
    }
}

extern "C" void kernel_launch(void* const* d_in, const int* in_sizes, int n_in,
                              void* d_out, int out_size, void* d_ws, size_t ws_size,
                              hipStream_t stream) {
    const float* x  = (const float*)d_in[0];
    const int*   ei = (const int*)d_in[1];
    const float* W1 = (const float*)d_in[2];
    const float* b1 = (const float*)d_in[3];
    const float* W2 = (const float*)d_in[4];
    const float* b2 = (const float*)d_in[5];
    float* out = (float*)d_out;
    const int* src = ei;
    const int* dst = ei + NEDGE;

    char* w = (char*)d_ws;
    size_t o = 0;
    auto alloc = [&](size_t bytes) -> char* {
        char* p = w + o;
        o += (bytes + 511) & ~(size_t)511;
        return p;
    };
    int*   bcnt   = (int*)alloc((size_t)NBKT * 4);
    float* dinv   = (float*)alloc((size_t)N_NODES * 4);
    int*   packed = (int*)alloc((size_t)NBKT * BCAP * 4);   // 14.0 MB
    float* h1s    = (float*)alloc((size_t)N_NODES * HID * 4);
    float* ys     = (float*)alloc((size_t)N_NODES * HID * 4);

    hipMemsetAsync(bcnt, 0, (size_t)NBKT * 4, stream);

    k_scatter<<<SC_NB, 256, 0, stream>>>(src, dst, bcnt, packed);
    k_dinvB<<<NBKT, 256, 0, stream>>>(bcnt, packed, dinv);
    k_gemm1<<<(N_NODES + 63) / 64, 256, 0, stream>>>(x, W1, dinv, h1s);
    k_agg1B<<<NBKT, 512, 0, stream>>>(h1s, packed, bcnt, dinv, b1, ys);
    k_agg2B<<<NBKT, 512, 0, stream>>>(ys, packed, bcnt, dinv, W2, b2, out);
}